// Round 15
// baseline (3797.262 us; speedup 1.0000x reference)
//
#include <hip/hip_runtime.h>
#include <hip/hip_fp16.h>

constexpr int Dm = 128;     // dims
constexpr int D4 = 32;      // dims/4
constexpr int Kc = 64;      // clusters
constexpr int NITER = 10;
constexpr double TOLd = 1e-4;
constexpr int BT  = 256;
constexpr int SLC = 256;    // slices for gather-sum (1 block/CU, 128KB LDS acc)
constexpr int IGB = 1024;   // init grid blocks (4 blocks/CU -> 4 waves/SIMD)
constexpr float MARGIN = 1e-2f;    // assign: fp32 top-2 gap below which fp64 (k_tie)
constexpr double IMARG = 4.0;      // init: fp16-screen margin (proven > worst-case err)

// ---- DPP quad-perm cross-lane adds (VALU pipe, not DS) ----------------------
__device__ __forceinline__ float dpp_qxor_f(float v, int ctrl) {
  int t = (ctrl == 0xB1)
    ? __builtin_amdgcn_update_dpp(0, __float_as_int(v), 0xB1, 0xF, 0xF, true)
    : __builtin_amdgcn_update_dpp(0, __float_as_int(v), 0x4E, 0xF, 0xF, true);
  return __int_as_float(t);
}
__device__ __forceinline__ double dpp_qxor_d(double v, int ctrl) {
  union { double d; int i[2]; } u; u.d = v;
  int lo, hi;
  if (ctrl == 0xB1) {
    lo = __builtin_amdgcn_update_dpp(0, u.i[0], 0xB1, 0xF, 0xF, true);
    hi = __builtin_amdgcn_update_dpp(0, u.i[1], 0xB1, 0xF, 0xF, true);
  } else {
    lo = __builtin_amdgcn_update_dpp(0, u.i[0], 0x4E, 0xF, 0xF, true);
    hi = __builtin_amdgcn_update_dpp(0, u.i[1], 0x4E, 0xF, 0xF, true);
  }
  union { int i[2]; double d; } r; r.i[0] = lo; r.i[1] = hi;
  return r.d;
}

// ---- argmax helpers: exact total order (value desc, index asc) => deterministic ----
__device__ __forceinline__ void wave_argmax(double& bd, int& bi) {
#pragma unroll
  for (int off = 32; off; off >>= 1) {
    double od = __shfl_down(bd, (unsigned)off, 64);
    int    oi = __shfl_down(bi, (unsigned)off, 64);
    if (od > bd || (od == bd && oi < bi)) { bd = od; bi = oi; }
  }
}

__device__ __forceinline__ void block_argmax(double& bd, int& bi, double* wd, int* wi) {
  wave_argmax(bd, bi);
  const int w = threadIdx.x >> 6;
  if ((threadIdx.x & 63) == 0) { wd[w] = bd; wi[w] = bi; }
  __syncthreads();
  bd = wd[0]; bi = wi[0];
#pragma unroll
  for (int j = 1; j < 4; ++j) {
    double od = wd[j]; int oi = wi[j];
    if (od > bd || (od == bd && oi < bi)) { bd = od; bi = oi; }
  }
  __syncthreads();
}

// one-time fp32 -> fp16 copy of X (screen operand)
__global__ __launch_bounds__(256) void k_prep(
    const float4* __restrict__ X4, uint4* __restrict__ Xh4, int ntot8) {
  const int gid = blockIdx.x * 256 + threadIdx.x;
  if (gid >= ntot8) return;
  float4 a = X4[gid * 2], b = X4[gid * 2 + 1];
  __half2 h0 = __floats2half2_rn(a.x, a.y);
  __half2 h1 = __floats2half2_rn(a.z, a.w);
  __half2 h2 = __floats2half2_rn(b.x, b.y);
  __half2 h3 = __floats2half2_rn(b.z, b.w);
  uint4 o;
  o.x = *(unsigned int*)&h0; o.y = *(unsigned int*)&h1;
  o.z = *(unsigned int*)&h2; o.w = *(unsigned int*)&h3;
  Xh4[gid] = o;
}

// 4 threads/point, grid-stride; partials = gridDim (IGB)
__global__ __launch_bounds__(BT) void k_init_first(
    const float* __restrict__ X, float* __restrict__ Cout, double* __restrict__ Cd,
    double* __restrict__ x2d, double* __restrict__ mind,
    double* __restrict__ opd, int* __restrict__ opi, int* __restrict__ done_flag, int N) {
  __shared__ double cent[Dm];
  __shared__ double wd[4]; __shared__ int wi[4];
  const int tid = threadIdx.x;
  if (tid < Dm) cent[tid] = (double)X[tid];
  if (blockIdx.x == 0) {
    if (tid == 0) *done_flag = 0;
    if (tid < Dm) { Cout[tid] = X[tid]; Cd[tid] = (double)X[tid]; }
  }
  __syncthreads();
  double c2 = 0.0;
  for (int d = 0; d < Dm; ++d) c2 += cent[d] * cent[d];
  const int g = tid >> 2, Q = tid & 3;
  const double* cq = cent + Q * 32;
  const int STRIDE = IGB * 64;
  double bd = -1.0; int bi = 0x7fffffff;
  for (int n = blockIdx.x * 64 + g; n < N; n += STRIDE) {
    const float4* xr = (const float4*)(X + (size_t)n * Dm + Q * 32);
    double a0 = 0, a1 = 0, a2 = 0, a3 = 0;
    double x0 = 0, x1 = 0, x2 = 0, x3 = 0;
#pragma unroll
    for (int q = 0; q < 8; ++q) {
      float4 xv = xr[q];
      a0 += (double)xv.x * cq[4*q+0]; a1 += (double)xv.y * cq[4*q+1];
      a2 += (double)xv.z * cq[4*q+2]; a3 += (double)xv.w * cq[4*q+3];
      x0 += (double)xv.x * xv.x; x1 += (double)xv.y * xv.y;
      x2 += (double)xv.z * xv.z; x3 += (double)xv.w * xv.w;
    }
    double dq = (a0 + a1) + (a2 + a3);
    double d1 = dq + dpp_qxor_d(dq, 0xB1);
    double dot = d1 + dpp_qxor_d(d1, 0x4E);
    double xq = (x0 + x1) + (x2 + x3);
    double xA = xq + dpp_qxor_d(xq, 0xB1);
    double xx = xA + dpp_qxor_d(xA, 0x4E);
    if (Q == 0) {
      x2d[n] = xx;
      double d2 = c2 + xx - 2.0 * dot; if (d2 < 0.0) d2 = 0.0;
      mind[n] = d2;
      if (d2 > bd) { bd = d2; bi = n; }   // ascending n, strict > => first index
    }
  }
  block_argmax(bd, bi, wd, wi);
  if (tid == 0) { opd[blockIdx.x] = bd; opi[blockIdx.x] = bi; }
}

// fused pick+step with fp16 SCREEN + exact fp64 fallback. 3-deep prefetch:
// with ~3 grid-stride iters/thread at IGB=1024, warmup issues ALL chunks ->
// max MLP. Screen margin IMARG=4 > proven worst-case error (~2.7), so skipped
// points provably can't change mind. Fallback path math bit-identical to R13.
__global__ __launch_bounds__(BT, 4) void k_init_step_h(
    const float* __restrict__ X, const __half* __restrict__ Xh,
    float* __restrict__ Cout, double* __restrict__ Cd,
    const double* __restrict__ x2d, double* __restrict__ mind,
    const double* __restrict__ ipd, const int* __restrict__ ipi,
    double* __restrict__ opd, int* __restrict__ opi, int N, int nparts, int ci) {
  __shared__ double cent[Dm];
  __shared__ float centf[Dm];
  __shared__ double wd[4]; __shared__ int wi[4];
  __shared__ double s_c2;
  const int tid = threadIdx.x;
  double bd = -1.0; int bi = 0x7fffffff;
  for (int t = tid; t < nparts; t += BT) {
    double d = ipd[t]; int id = ipi[t];
    if (d > bd || (d == bd && id < bi)) { bd = d; bi = id; }
  }
  block_argmax(bd, bi, wd, wi);
  const int idx = bi;
  if (tid < Dm) {
    float v = X[(size_t)idx * Dm + tid];
    cent[tid]  = (double)v;
    centf[tid] = v;                      // exact fp32 centroid for the screen
    if (blockIdx.x == 0) {
      Cout[(size_t)ci * Dm + tid] = v;
      Cd[(size_t)ci * Dm + tid]   = (double)v;
    }
  }
  __syncthreads();
  if (tid == 0) {   // serial ascending: bit-identical c2 (do NOT reorder)
    double s = 0.0;
    for (int d = 0; d < Dm; ++d) s += cent[d] * cent[d];
    s_c2 = s;
  }
  __syncthreads();
  const double c2 = s_c2;
  const int g = tid >> 2, Q = tid & 3;
  const double* cq = cent + Q * 32;
  const float2* cf2 = (const float2*)(centf + Q * 32);   // 16 float2
  const int STRIDE = IGB * 64;
  bd = -1.0; bi = 0x7fffffff;

  auto LOADH = [&](int n, uint4* h, double& m, double& xx) {
    const uint4* hr = (const uint4*)(Xh + (size_t)n * Dm + Q * 32);
#pragma unroll
    for (int q = 0; q < 4; ++q) h[q] = hr[q];
    m = mind[n]; xx = x2d[n];            // uniform within 4-lane group
  };
  auto PROCH = [&](int n, const uint4* h, double m, double xx) {
    float a0 = 0.f, a1 = 0.f;
#pragma unroll
    for (int j = 0; j < 4; ++j) {
      union { uint4 u; __half2 p[4]; } U; U.u = h[j];
#pragma unroll
      for (int t = 0; t < 4; ++t) {
        float2 xf = __half22float2(U.p[t]);
        float2 c  = cf2[j * 4 + t];
        a0 = fmaf(xf.x, c.x, a0); a1 = fmaf(xf.y, c.y, a1);
      }
    }
    float dq = a0 + a1;
    dq += dpp_qxor_f(dq, 0xB1); dq += dpp_qxor_f(dq, 0x4E);   // all 4 lanes get sum
    const double ds = c2 + xx - 2.0 * (double)dq;
    double mm = m;
    if (!(ds - m > IMARG)) {             // group-uniform: possible update -> exact
      const float4* xr = (const float4*)(X + (size_t)n * Dm + Q * 32);
      double b0 = 0, b1 = 0, b2 = 0, b3 = 0;
#pragma unroll
      for (int q = 0; q < 8; ++q) {
        float4 v = xr[q];
        b0 += (double)v.x * cq[4*q+0]; b1 += (double)v.y * cq[4*q+1];
        b2 += (double)v.z * cq[4*q+2]; b3 += (double)v.w * cq[4*q+3];
      }
      double dqd = (b0 + b1) + (b2 + b3);
      double d1 = dqd + dpp_qxor_d(dqd, 0xB1);
      double dot = d1 + dpp_qxor_d(d1, 0x4E);
      double d2v = c2 + xx - 2.0 * dot; if (d2v < 0.0) d2v = 0.0;
      if (d2v < mm) mm = d2v;
      if (Q == 0) mind[n] = mm;
    }
    if (Q == 0 && mm > bd) { bd = mm; bi = n; }   // ascending n per lane
  };

  uint4 hA[4], hB[4], hC[4];
  double mA = 0, xxA = 0, mB = 0, xxB = 0, mC = 0, xxC = 0;
  int n = blockIdx.x * 64 + g;           // IGB*64 = 65536 < N: first n valid
  LOADH(n, hA, mA, xxA);
  if (n + STRIDE < N) LOADH(n + STRIDE, hB, mB, xxB);
  if (n + 2 * STRIDE < N) LOADH(n + 2 * STRIDE, hC, mC, xxC);
  for (;;) {
    PROCH(n, hA, mA, xxA);
    if (n + 3 * STRIDE < N) LOADH(n + 3 * STRIDE, hA, mA, xxA);
    n += STRIDE; if (n >= N) break;
    PROCH(n, hB, mB, xxB);
    if (n + 3 * STRIDE < N) LOADH(n + 3 * STRIDE, hB, mB, xxB);
    n += STRIDE; if (n >= N) break;
    PROCH(n, hC, mC, xxC);
    if (n + 3 * STRIDE < N) LOADH(n + 3 * STRIDE, hC, mC, xxC);
    n += STRIDE; if (n >= N) break;
  }
  block_argmax(bd, bi, wd, wi);
  if (tid == 0) { opd[blockIdx.x] = bd; opi[blockIdx.x] = bi; }
}

// fp32 fallback step (3-deep pipeline) — used if ws too small for Xh
__global__ __launch_bounds__(BT, 1) void k_init_step(
    const float* __restrict__ X, float* __restrict__ Cout, double* __restrict__ Cd,
    const double* __restrict__ x2d, double* __restrict__ mind,
    const double* __restrict__ ipd, const int* __restrict__ ipi,
    double* __restrict__ opd, int* __restrict__ opi, int N, int nparts, int ci) {
  __shared__ double cent[Dm];
  __shared__ double wd[4]; __shared__ int wi[4];
  __shared__ double s_c2;
  const int tid = threadIdx.x;
  double bd = -1.0; int bi = 0x7fffffff;
  for (int t = tid; t < nparts; t += BT) {
    double d = ipd[t]; int id = ipi[t];
    if (d > bd || (d == bd && id < bi)) { bd = d; bi = id; }
  }
  block_argmax(bd, bi, wd, wi);
  const int idx = bi;
  if (tid < Dm) {
    float v = X[(size_t)idx * Dm + tid];
    cent[tid] = (double)v;
    if (blockIdx.x == 0) {
      Cout[(size_t)ci * Dm + tid] = v;
      Cd[(size_t)ci * Dm + tid]   = (double)v;
    }
  }
  __syncthreads();
  if (tid == 0) {
    double s = 0.0;
    for (int d = 0; d < Dm; ++d) s += cent[d] * cent[d];
    s_c2 = s;
  }
  __syncthreads();
  const double c2 = s_c2;
  const int g = tid >> 2, Q = tid & 3;
  const double* cq = cent + Q * 32;
  const int STRIDE = IGB * 64;
  bd = -1.0; bi = 0x7fffffff;
  auto LOADB = [&](int n, float4* xv, double& m, double& xx) {
    const float4* xr = (const float4*)(X + (size_t)n * Dm + Q * 32);
#pragma unroll
    for (int q = 0; q < 8; ++q) xv[q] = xr[q];
    if (Q == 0) { m = mind[n]; xx = x2d[n]; }
  };
  auto PROCB = [&](int n, const float4* xv, double m, double xx) {
    double a0 = 0, a1 = 0, a2 = 0, a3 = 0;
#pragma unroll
    for (int q = 0; q < 8; ++q) {
      float4 v = xv[q];
      a0 += (double)v.x * cq[4*q+0]; a1 += (double)v.y * cq[4*q+1];
      a2 += (double)v.z * cq[4*q+2]; a3 += (double)v.w * cq[4*q+3];
    }
    double dq = (a0 + a1) + (a2 + a3);
    double d1 = dq + dpp_qxor_d(dq, 0xB1);
    double dot = d1 + dpp_qxor_d(d1, 0x4E);
    if (Q == 0) {
      double d2 = c2 + xx - 2.0 * dot; if (d2 < 0.0) d2 = 0.0;
      double mm = m; if (d2 < mm) mm = d2;
      mind[n] = mm;
      if (mm > bd) { bd = mm; bi = n; }
    }
  };
  float4 xA[8], xB[8], xC[8];
  double mA = 0, xxA = 0, mB = 0, xxB = 0, mC = 0, xxC = 0;
  int n = blockIdx.x * 64 + g;
  if (n < N) {
    LOADB(n, xA, mA, xxA);
    if (n + STRIDE < N) LOADB(n + STRIDE, xB, mB, xxB);
    if (n + 2 * STRIDE < N) LOADB(n + 2 * STRIDE, xC, mC, xxC);
    for (;;) {
      PROCB(n, xA, mA, xxA);
      if (n + 3 * STRIDE < N) LOADB(n + 3 * STRIDE, xA, mA, xxA);
      n += STRIDE; if (n >= N) break;
      PROCB(n, xB, mB, xxB);
      if (n + 3 * STRIDE < N) LOADB(n + 3 * STRIDE, xB, mB, xxB);
      n += STRIDE; if (n >= N) break;
      PROCB(n, xC, mC, xxC);
      if (n + 3 * STRIDE < N) LOADB(n + 3 * STRIDE, xC, mC, xxC);
      n += STRIDE; if (n >= N) break;
    }
  }
  block_argmax(bd, bi, wd, wi);
  if (tid == 0) { opd[blockIdx.x] = bd; opi[blockIdx.x] = bi; }
}

// final pick (single block): choose C[63], per-row c2 for Lloyd, reset tie_cnt
__global__ __launch_bounds__(256) void k_pick(
    const float* __restrict__ X, float* __restrict__ Cout, double* __restrict__ Cd,
    const double* __restrict__ ipd, const int* __restrict__ ipi, int nparts, int ci,
    double* __restrict__ c2d, float* __restrict__ c2f, int* __restrict__ tie_cnt) {
  __shared__ double cent[Dm];
  __shared__ double wd[4]; __shared__ int wi[4];
  const int tid = threadIdx.x;
  double bd = -1.0; int bi = 0x7fffffff;
  for (int t = tid; t < nparts; t += 256) {
    double d = ipd[t]; int id = ipi[t];
    if (d > bd || (d == bd && id < bi)) { bd = d; bi = id; }
  }
  block_argmax(bd, bi, wd, wi);
  const int idx = bi;
  if (tid < Dm) {
    float v = X[(size_t)idx * Dm + tid];
    cent[tid] = (double)v;
    Cout[(size_t)ci * Dm + tid] = v;
    Cd[(size_t)ci * Dm + tid]   = (double)v;
  }
  __syncthreads();
  if (tid < Kc) {
    double s = 0.0;
    if (tid == ci) { for (int d = 0; d < Dm; ++d) s += cent[d] * cent[d]; }
    else { for (int d = 0; d < Dm; ++d) { double v = Cd[(size_t)tid * Dm + d]; s += v * v; } }
    c2d[tid] = s; c2f[tid] = (float)s;
  }
  if (tid == 0) *tie_cnt = 0;
}

// fp32 screen: 4-lane group (lane = 32 dims) x 4 points per group (empirical wall
// ~100us, R7-R12; residency forcing failed twice). C in padded LDS.
__global__ __launch_bounds__(256, 2) void k_assign(
    const float* __restrict__ X, const float* __restrict__ Cf,
    const float* __restrict__ c2f,
    unsigned char* __restrict__ lbl,
    int* __restrict__ tie_list, int* __restrict__ tie_cnt,
    const int* __restrict__ done_flag, int N) {
  if (*done_flag) return;
  __shared__ float4 cs[Kc * 35];
  __shared__ float c2s[Kc];
  const int tid = threadIdx.x;
  for (int e = tid; e < Kc * D4; e += 256) {
    const int k = e >> 5, j = e & 31;
    cs[k * 35 + (j >> 3) * 9 + (j & 7)] = ((const float4*)Cf)[e];
  }
  if (tid < Kc) c2s[tid] = c2f[tid];
  __syncthreads();
  const int g = tid >> 2, Q = tid & 3;
  const int n0 = blockIdx.x * 256 + g * 4;
  float4 xv[4][8];
#pragma unroll
  for (int j = 0; j < 4; ++j) {
    int p = n0 + j; if (p > N - 1) p = N - 1;
    const float4* xr = (const float4*)(X + (size_t)p * Dm + Q * 32);
#pragma unroll
    for (int q = 0; q < 8; ++q) xv[j][q] = xr[q];
  }
  const float4* myc = cs + Q * 9;
  float best = 3.4028235e38f, second = 3.4028235e38f; int bk = 0;
  for (int k = 0; k < Kc; ++k) {
    const float4* ck = myc + k * 35;
    float a00=0,a01=0,a02=0,a03=0, a10=0,a11=0,a12=0,a13=0;
    float a20=0,a21=0,a22=0,a23=0, a30=0,a31=0,a32=0,a33=0;
#pragma unroll
    for (int q = 0; q < 8; ++q) {
      float4 cv = ck[q];
      a00 += xv[0][q].x*cv.x; a01 += xv[0][q].y*cv.y; a02 += xv[0][q].z*cv.z; a03 += xv[0][q].w*cv.w;
      a10 += xv[1][q].x*cv.x; a11 += xv[1][q].y*cv.y; a12 += xv[1][q].z*cv.z; a13 += xv[1][q].w*cv.w;
      a20 += xv[2][q].x*cv.x; a21 += xv[2][q].y*cv.y; a22 += xv[2][q].z*cv.z; a23 += xv[2][q].w*cv.w;
      a30 += xv[3][q].x*cv.x; a31 += xv[3][q].y*cv.y; a32 += xv[3][q].z*cv.z; a33 += xv[3][q].w*cv.w;
    }
    float d0 = (a00 + a01) + (a02 + a03);
    float d1 = (a10 + a11) + (a12 + a13);
    float d2 = (a20 + a21) + (a22 + a23);
    float d3 = (a30 + a31) + (a32 + a33);
    d0 += dpp_qxor_f(d0, 0xB1); d0 += dpp_qxor_f(d0, 0x4E);
    d1 += dpp_qxor_f(d1, 0xB1); d1 += dpp_qxor_f(d1, 0x4E);
    d2 += dpp_qxor_f(d2, 0xB1); d2 += dpp_qxor_f(d2, 0x4E);
    d3 += dpp_qxor_f(d3, 0xB1); d3 += dpp_qxor_f(d3, 0x4E);
    float mydot = (Q == 0) ? d0 : (Q == 1) ? d1 : (Q == 2) ? d2 : d3;
    float sc = c2s[k] - 2.f * mydot;
    if (sc < best) { second = best; best = sc; bk = k; }
    else if (sc < second) second = sc;
  }
  const int n = n0 + Q;
  if (n < N) {
    lbl[n] = (unsigned char)bk;
    if (second - best < MARGIN) {
      int t = atomicAdd(tie_cnt, 1);
      tie_list[t] = n;
    }
  }
}

// fp64 tie resolution: one WAVE per tie point; lane = cluster.
__global__ __launch_bounds__(256) void k_tie(
    const float* __restrict__ X, const double* __restrict__ Cd,
    const double* __restrict__ c2d,
    const int* __restrict__ tie_list, const int* __restrict__ tie_cnt,
    unsigned char* __restrict__ lbl, const int* __restrict__ done_flag) {
  if (*done_flag) return;
  const int nt = *tie_cnt;
  const int gw = (int)((blockIdx.x * 256 + threadIdx.x) >> 6);
  const int lane = threadIdx.x & 63;
  const int nwaves = gridDim.x * 4;
  const double* cp = Cd + (size_t)lane * Dm;
  const double myc2 = c2d[lane];
  for (int t = gw; t < nt; t += nwaves) {
    const int n = tie_list[t];
    const float4* xr = (const float4*)(X + (size_t)n * Dm);
    double a0 = 0, a1 = 0, a2 = 0, a3 = 0;
#pragma unroll 8
    for (int q = 0; q < D4; ++q) {
      float4 xv = xr[q];
      a0 += (double)xv.x * cp[4*q+0]; a1 += (double)xv.y * cp[4*q+1];
      a2 += (double)xv.z * cp[4*q+2]; a3 += (double)xv.w * cp[4*q+3];
    }
    double sc = myc2 - 2.0 * ((a0 + a1) + (a2 + a3));
    int bk = lane;
#pragma unroll
    for (int off = 32; off; off >>= 1) {
      double osc = __shfl_down(sc, (unsigned)off, 64);
      int    obk = __shfl_down(bk, (unsigned)off, 64);
      if (osc < sc || (osc == sc && obk < bk)) { sc = osc; bk = obk; }
    }
    if (lane == 0) lbl[n] = (unsigned char)bk;
  }
}

// streaming gather-sum with 4-stage software-pipelined prefetch (deterministic).
__global__ __launch_bounds__(256) void k_sum(
    const float* __restrict__ X, const unsigned char* __restrict__ lbl,
    double* __restrict__ spart, int* __restrict__ cpart,
    const int* __restrict__ done_flag, int N, int chunk) {
  if (*done_flag) return;
  __shared__ double acc[2][Kc * Dm];
  __shared__ unsigned int sl[1024];
  __shared__ int cnt[Kc];
  const int tid = threadIdx.x;
  const int s = blockIdx.x;
  const int n0 = s * chunk;
  const int nrows = (N - n0 < chunk) ? (N - n0) : chunk;
  for (int e = tid; e < 2 * Kc * Dm; e += 256) ((double*)acc)[e] = 0.0;
  if (tid < Kc) cnt[tid] = 0;
  const int nw = (nrows > 0) ? ((nrows + 3) >> 2) : 0;
  const unsigned int* lw = (const unsigned int*)(lbl + n0);
  for (int w = tid; w < nw; w += 256) sl[w] = lw[w];
  __syncthreads();
  for (int i = tid; i < nrows; i += 256)
    atomicAdd(&cnt[(sl[i >> 2] >> ((i & 3) * 8)) & 255], 1);
  const int w = tid >> 6, L = tid & 63;
  const int parity = w >> 1, half = w & 1;
  double* ac = acc[parity] + half * 64 + L;
  const float* Xb = X + (size_t)n0 * Dm + half * 64 + L;
  auto LOADC = [&](int base, float* f, int* c) {
#pragma unroll
    for (int u = 0; u < 8; ++u) {
      const int i = base + 2 * u;
      if (i < nrows) {
        c[u] = (int)((sl[i >> 2] >> ((i & 3) * 8)) & 255u);
        f[u] = Xb[(size_t)i * Dm];
      } else c[u] = -1;
    }
  };
  auto PROCC = [&](const float* f, const int* c) {
#pragma unroll
    for (int u = 0; u < 8; ++u)
      if (c[u] >= 0) ac[c[u] * Dm] += (double)f[u];
  };
  float fA[8], fB[8], fC[8], fD[8];
  int   cA[8], cB[8], cC[8], cD[8];
  const int CS = 16;
  LOADC(parity,          fA, cA);
  LOADC(parity + CS,     fB, cB);
  LOADC(parity + 2 * CS, fC, cC);
  for (int cb = parity; cb < nrows; cb += 4 * CS) {
    LOADC(cb + 3 * CS, fD, cD); PROCC(fA, cA);
    LOADC(cb + 4 * CS, fA, cA); PROCC(fB, cB);
    LOADC(cb + 5 * CS, fB, cB); PROCC(fC, cC);
    LOADC(cb + 6 * CS, fC, cC); PROCC(fD, cD);
  }
  __syncthreads();
  for (int e = tid; e < Kc * Dm; e += 256)
    spart[(size_t)s * (Kc * Dm) + e] = acc[0][e] + acc[1][e];
  if (tid < Kc) cpart[s * Kc + tid] = cnt[tid];
}

// per-cluster reduce over slices (fixed ascending order) + mean/shift/c2
__global__ __launch_bounds__(128) void k_update1(
    float* __restrict__ Cout, double* __restrict__ Cd,
    double* __restrict__ c2d, float* __restrict__ c2f,
    const double* __restrict__ spart, const int* __restrict__ cpart,
    double* __restrict__ shiftk, int* __restrict__ empty,
    const int* __restrict__ done_flag, int nslc) {
  if (*done_flag) return;
  __shared__ double red[128];
  __shared__ int ired[128];
  const int k = blockIdx.x, d = threadIdx.x;
  int c = 0;
  for (int s = d; s < nslc; s += 128) c += cpart[s * Kc + k];
  ired[d] = c; __syncthreads();
  for (int t = 64; t; t >>= 1) { if (d < t) ired[d] += ired[d + t]; __syncthreads(); }
  const int cnt = ired[0];
  double sum = 0.0;
#pragma unroll 8
  for (int s = 0; s < nslc; ++s) sum += spart[(size_t)s * (Kc * Dm) + k * Dm + d];
  const double mean = sum / (double)(cnt > 1 ? cnt : 1);
  const double oldv = Cd[k * Dm + d];
  Cd[k * Dm + d] = mean; Cout[k * Dm + d] = (float)mean;
  red[d] = (cnt != 0) ? (mean - oldv) * (mean - oldv) : 0.0;
  __syncthreads();
  for (int t = 64; t; t >>= 1) { if (d < t) red[d] += red[d + t]; __syncthreads(); }
  if (d == 0) shiftk[k] = red[0];
  __syncthreads();
  red[d] = mean * mean; __syncthreads();
  for (int t = 64; t; t >>= 1) { if (d < t) red[d] += red[d + t]; __syncthreads(); }
  if (d == 0) { c2d[k] = red[0]; c2f[k] = (float)red[0]; empty[k] = (cnt == 0); }
}

__global__ void k_update2(const double* __restrict__ shiftk, const int* __restrict__ empty,
                          int* __restrict__ done_flag, int* __restrict__ has_empty,
                          int* __restrict__ tie_cnt) {
  if (*done_flag) return;
  if (threadIdx.x == 0) {
    double sh = 0.0; int any = 0;
    for (int k = 0; k < Kc; ++k) { sh += shiftk[k]; any |= empty[k]; }
    *has_empty = any;
    *tie_cnt = 0;
    if (!any && sh <= TOLd) *done_flag = 1;
  }
}

__global__ __launch_bounds__(BT) void k_far(
    const float* __restrict__ X, const double* __restrict__ Cd,
    const double* __restrict__ c2d, const double* __restrict__ x2d,
    const int* __restrict__ done_flag, const int* __restrict__ has_empty,
    const int* __restrict__ empty,
    double* __restrict__ opd, int* __restrict__ opi, int N) {
  if (*done_flag || !*has_empty) return;
  __shared__ int semp[Kc];
  __shared__ double wd[4]; __shared__ int wi[4];
  if ((int)threadIdx.x < Kc) semp[threadIdx.x] = empty[threadIdx.x];
  __syncthreads();
  const int n = blockIdx.x * BT + threadIdx.x;
  double bd = -1.0; int bi = 0x7fffffff;
  if (n < N) {
    const float4* xr = (const float4*)(X + (size_t)n * Dm);
    float4 xv[D4];
#pragma unroll
    for (int q = 0; q < D4; ++q) xv[q] = xr[q];
    double md = 1e300;
    for (int k = 0; k < Kc; ++k) {
      if (semp[k]) continue;
      double a0 = 0, a1 = 0, a2 = 0, a3 = 0;
      const double* cp = Cd + (size_t)k * Dm;
#pragma unroll
      for (int q = 0; q < D4; ++q) {
        a0 += (double)xv[q].x * cp[4*q+0]; a1 += (double)xv[q].y * cp[4*q+1];
        a2 += (double)xv[q].z * cp[4*q+2]; a3 += (double)xv[q].w * cp[4*q+3];
      }
      double d2v = c2d[k] + x2d[n] - 2.0 * ((a0 + a1) + (a2 + a3));
      if (d2v < 0.0) d2v = 0.0;
      if (d2v < md) md = d2v;
    }
    bd = md; bi = n;
  }
  block_argmax(bd, bi, wd, wi);
  if (threadIdx.x == 0) { opd[blockIdx.x] = bd; opi[blockIdx.x] = bi; }
}

__global__ __launch_bounds__(BT) void k_fix(
    const float* __restrict__ X, float* __restrict__ Cout, double* __restrict__ Cd,
    double* __restrict__ c2d, float* __restrict__ c2f,
    const int* __restrict__ done_flag, const int* __restrict__ has_empty,
    const int* __restrict__ empty,
    const double* __restrict__ ipd, const int* __restrict__ ipi, int nparts) {
  if (*done_flag || !*has_empty) return;
  const int lane = threadIdx.x & 63;
  double bd = -1.0; int bi = 0x7fffffff;
  for (int t = lane; t < nparts; t += 64) {
    double d = ipd[t]; int id = ipi[t];
    if (d > bd || (d == bd && id < bi)) { bd = d; bi = id; }
  }
  wave_argmax(bd, bi);
  const int far = __shfl(bi, 0, 64);
  for (int e = threadIdx.x; e < Kc * Dm; e += BT) {
    if (empty[e >> 7]) {
      float v = X[(size_t)far * Dm + (e & 127)];
      Cout[e] = v; Cd[e] = (double)v;
    }
  }
  __syncthreads();
  if ((int)threadIdx.x < Kc && empty[threadIdx.x]) {
    double s2 = 0.0;
    for (int d = 0; d < Dm; ++d) { double v = Cd[(size_t)threadIdx.x * Dm + d]; s2 += v * v; }
    c2d[threadIdx.x] = s2; c2f[threadIdx.x] = (float)s2;
  }
}

extern "C" void kernel_launch(void* const* d_in, const int* in_sizes, int n_in,
                              void* d_out, int out_size, void* d_ws, size_t ws_size,
                              hipStream_t stream) {
  const float* X = (const float*)d_in[0];
  const int N = in_sizes[0] / Dm;          // 200000
  float* Cout = (float*)d_out;
  (void)n_in; (void)out_size;

  char* w = (char*)d_ws;
  auto alloc = [&](size_t bytes) -> void* {
    void* p = (void*)w; w += (bytes + 255) & ~(size_t)255; return p;
  };
  const size_t NP = ((size_t)N + 255) & ~(size_t)255;
  const int IB  = (N + BT - 1) / BT;       // 782 blocks (1 pt/thread kernels)
  const int ABL = (N + 255) / 256;         // 782 assign blocks
  double* x2d  = (double*)alloc(NP * 8);
  const size_t spart_bytes = (size_t)SLC * Kc * Dm * 8;   // 16.8 MB
  const size_t union_bytes = (spart_bytes > NP * 8) ? spart_bytes : NP * 8;
  double* mind  = (double*)alloc(union_bytes);
  double* spart = mind;
  double* pd0  = (double*)alloc(4096 * 8);
  double* pd1  = (double*)alloc(4096 * 8);
  int*    pi0  = (int*)alloc(4096 * 4);
  int*    pi1  = (int*)alloc(4096 * 4);
  double* Cd   = (double*)alloc((size_t)Kc * Dm * 8);
  double* c2d  = (double*)alloc(Kc * 8);
  float*  c2f  = (float*)alloc(Kc * 4);
  int*    cpart = (int*)alloc(SLC * Kc * 4);
  double* shiftk = (double*)alloc(Kc * 8);
  unsigned char* lbl = (unsigned char*)alloc(NP);
  int*    tie_list = (int*)alloc(NP * 4);
  int*    tie_cnt  = (int*)alloc(4);
  int*    done  = (int*)alloc(4);
  int*    hasem = (int*)alloc(4);
  int*    empty = (int*)alloc(Kc * 4);
  __half* Xh = (__half*)alloc((size_t)N * Dm * 2);        // 51.2 MB fp16 screen copy
  const bool use_h = ((size_t)(w - (char*)d_ws) <= ws_size);

  double* pd[2] = {pd0, pd1};
  int*    pi[2] = {pi0, pi1};

  // ---- farthest-point init: C[0]=X[0], then 63 sequential argmax picks ----
  if (use_h) {
    const int ntot8 = N * Dm / 8;          // 3.2M uint4 groups
    k_prep<<<(ntot8 + 255) / 256, 256, 0, stream>>>((const float4*)X, (uint4*)Xh, ntot8);
  }
  k_init_first<<<IGB, BT, 0, stream>>>(X, Cout, Cd, x2d, mind, pd[0], pi[0], done, N);
  for (int i = 1; i <= 62; ++i) {
    const int rb = (i + 1) & 1, wb = i & 1;
    if (use_h)
      k_init_step_h<<<IGB, BT, 0, stream>>>(X, Xh, Cout, Cd, x2d, mind, pd[rb], pi[rb],
                                            pd[wb], pi[wb], N, IGB, i);
    else
      k_init_step<<<IGB, BT, 0, stream>>>(X, Cout, Cd, x2d, mind, pd[rb], pi[rb],
                                          pd[wb], pi[wb], N, IGB, i);
  }
  k_pick<<<1, 256, 0, stream>>>(X, Cout, Cd, pd[0], pi[0], IGB, 63,
                                c2d, c2f, tie_cnt);   // step 62 wrote buf 0

  // ---- 10 Lloyd iterations ----
  const int chunk = ((N + SLC - 1) / SLC + 3) & ~3;   // 784
  for (int it = 0; it < NITER; ++it) {
    k_assign<<<ABL, 256, 0, stream>>>(X, Cout, c2f, lbl, tie_list, tie_cnt, done, N);
    k_tie<<<128, 256, 0, stream>>>(X, Cd, c2d, tie_list, tie_cnt, lbl, done);
    k_sum<<<SLC, 256, 0, stream>>>(X, lbl, spart, cpart, done, N, chunk);
    k_update1<<<Kc, 128, 0, stream>>>(Cout, Cd, c2d, c2f, spart, cpart,
                                      shiftk, empty, done, SLC);
    k_update2<<<1, 64, 0, stream>>>(shiftk, empty, done, hasem, tie_cnt);
    k_far<<<IB, BT, 0, stream>>>(X, Cd, c2d, x2d, done, hasem, empty, pd0, pi0, N);
    k_fix<<<1, BT, 0, stream>>>(X, Cout, Cd, c2d, c2f, done, hasem, empty, pd0, pi0, IB);
  }
}

// Round 16
// 3010.032 us; speedup vs baseline: 1.2615x; 1.2615x over previous
//
#include <hip/hip_runtime.h>
#include <hip/hip_fp16.h>

constexpr int Dm = 128;     // dims
constexpr int D4 = 32;      // dims/4
constexpr int Kc = 64;      // clusters
constexpr int NITER = 10;
constexpr double TOLd = 1e-4;
constexpr int BT  = 256;
constexpr int SLC = 256;    // slices for gather-sum (1 block/CU, 128KB LDS acc)
constexpr int IGB = 512;    // init grid blocks — verified optimum (1024 regressed R10+R15)
constexpr float MARGIN = 1e-2f;    // assign: fp32 top-2 gap below which fp64 (k_tie)
constexpr double IMARG = 4.0;      // init: fp16-screen margin (proven > worst-case err)

// ---- DPP quad-perm cross-lane adds (VALU pipe, not DS) ----------------------
__device__ __forceinline__ float dpp_qxor_f(float v, int ctrl) {
  int t = (ctrl == 0xB1)
    ? __builtin_amdgcn_update_dpp(0, __float_as_int(v), 0xB1, 0xF, 0xF, true)
    : __builtin_amdgcn_update_dpp(0, __float_as_int(v), 0x4E, 0xF, 0xF, true);
  return __int_as_float(t);
}
__device__ __forceinline__ double dpp_qxor_d(double v, int ctrl) {
  union { double d; int i[2]; } u; u.d = v;
  int lo, hi;
  if (ctrl == 0xB1) {
    lo = __builtin_amdgcn_update_dpp(0, u.i[0], 0xB1, 0xF, 0xF, true);
    hi = __builtin_amdgcn_update_dpp(0, u.i[1], 0xB1, 0xF, 0xF, true);
  } else {
    lo = __builtin_amdgcn_update_dpp(0, u.i[0], 0x4E, 0xF, 0xF, true);
    hi = __builtin_amdgcn_update_dpp(0, u.i[1], 0x4E, 0xF, 0xF, true);
  }
  union { int i[2]; double d; } r; r.i[0] = lo; r.i[1] = hi;
  return r.d;
}

// ---- argmax helpers: exact total order (value desc, index asc) => deterministic ----
__device__ __forceinline__ void wave_argmax(double& bd, int& bi) {
#pragma unroll
  for (int off = 32; off; off >>= 1) {
    double od = __shfl_down(bd, (unsigned)off, 64);
    int    oi = __shfl_down(bi, (unsigned)off, 64);
    if (od > bd || (od == bd && oi < bi)) { bd = od; bi = oi; }
  }
}

__device__ __forceinline__ void block_argmax(double& bd, int& bi, double* wd, int* wi) {
  wave_argmax(bd, bi);
  const int w = threadIdx.x >> 6;
  if ((threadIdx.x & 63) == 0) { wd[w] = bd; wi[w] = bi; }
  __syncthreads();
  bd = wd[0]; bi = wi[0];
#pragma unroll
  for (int j = 1; j < 4; ++j) {
    double od = wd[j]; int oi = wi[j];
    if (od > bd || (od == bd && oi < bi)) { bd = od; bi = oi; }
  }
  __syncthreads();
}

// one-time fp32 -> fp16 copy of X (screen operand)
__global__ __launch_bounds__(256) void k_prep(
    const float4* __restrict__ X4, uint4* __restrict__ Xh4, int ntot8) {
  const int gid = blockIdx.x * 256 + threadIdx.x;
  if (gid >= ntot8) return;
  float4 a = X4[gid * 2], b = X4[gid * 2 + 1];
  __half2 h0 = __floats2half2_rn(a.x, a.y);
  __half2 h1 = __floats2half2_rn(a.z, a.w);
  __half2 h2 = __floats2half2_rn(b.x, b.y);
  __half2 h3 = __floats2half2_rn(b.z, b.w);
  uint4 o;
  o.x = *(unsigned int*)&h0; o.y = *(unsigned int*)&h1;
  o.z = *(unsigned int*)&h2; o.w = *(unsigned int*)&h3;
  Xh4[gid] = o;
}

// 4 threads/point, grid-stride; partials = gridDim (IGB)
__global__ __launch_bounds__(BT) void k_init_first(
    const float* __restrict__ X, float* __restrict__ Cout, double* __restrict__ Cd,
    double* __restrict__ x2d, double* __restrict__ mind,
    double* __restrict__ opd, int* __restrict__ opi, int* __restrict__ done_flag, int N) {
  __shared__ double cent[Dm];
  __shared__ double wd[4]; __shared__ int wi[4];
  const int tid = threadIdx.x;
  if (tid < Dm) cent[tid] = (double)X[tid];
  if (blockIdx.x == 0) {
    if (tid == 0) *done_flag = 0;
    if (tid < Dm) { Cout[tid] = X[tid]; Cd[tid] = (double)X[tid]; }
  }
  __syncthreads();
  double c2 = 0.0;
  for (int d = 0; d < Dm; ++d) c2 += cent[d] * cent[d];
  const int g = tid >> 2, Q = tid & 3;
  const double* cq = cent + Q * 32;
  const int STRIDE = IGB * 64;
  double bd = -1.0; int bi = 0x7fffffff;
  for (int n = blockIdx.x * 64 + g; n < N; n += STRIDE) {
    const float4* xr = (const float4*)(X + (size_t)n * Dm + Q * 32);
    double a0 = 0, a1 = 0, a2 = 0, a3 = 0;
    double x0 = 0, x1 = 0, x2 = 0, x3 = 0;
#pragma unroll
    for (int q = 0; q < 8; ++q) {
      float4 xv = xr[q];
      a0 += (double)xv.x * cq[4*q+0]; a1 += (double)xv.y * cq[4*q+1];
      a2 += (double)xv.z * cq[4*q+2]; a3 += (double)xv.w * cq[4*q+3];
      x0 += (double)xv.x * xv.x; x1 += (double)xv.y * xv.y;
      x2 += (double)xv.z * xv.z; x3 += (double)xv.w * xv.w;
    }
    double dq = (a0 + a1) + (a2 + a3);
    double d1 = dq + dpp_qxor_d(dq, 0xB1);
    double dot = d1 + dpp_qxor_d(d1, 0x4E);
    double xq = (x0 + x1) + (x2 + x3);
    double xA = xq + dpp_qxor_d(xq, 0xB1);
    double xx = xA + dpp_qxor_d(xA, 0x4E);
    if (Q == 0) {
      x2d[n] = xx;
      double d2 = c2 + xx - 2.0 * dot; if (d2 < 0.0) d2 = 0.0;
      mind[n] = d2;
      if (d2 > bd) { bd = d2; bi = n; }   // ascending n, strict > => first index
    }
  }
  block_argmax(bd, bi, wd, wi);
  if (tid == 0) { opd[blockIdx.x] = bd; opi[blockIdx.x] = bi; }
}

// fused pick+step with fp16 SCREEN + exact fp64 fallback.
// Screen: ds = c2 + x2d[n] - 2*dot(Xh row, centf) with |err| < 2.7 (proven:
// |x|,|c| <= 6.5 -> 128*6.5^2*9.8e-4 + fp32 accum). ds - mind > IMARG(4) =>
// min provably unchanged -> skip fp32 row. Else: exact fp64 path, bit-identical.
__global__ __launch_bounds__(BT, 2) void k_init_step_h(
    const float* __restrict__ X, const __half* __restrict__ Xh,
    float* __restrict__ Cout, double* __restrict__ Cd,
    const double* __restrict__ x2d, double* __restrict__ mind,
    const double* __restrict__ ipd, const int* __restrict__ ipi,
    double* __restrict__ opd, int* __restrict__ opi, int N, int nparts, int ci) {
  __shared__ double cent[Dm];
  __shared__ float centf[Dm];
  __shared__ double wd[4]; __shared__ int wi[4];
  __shared__ double s_c2;
  const int tid = threadIdx.x;
  double bd = -1.0; int bi = 0x7fffffff;
  for (int t = tid; t < nparts; t += BT) {
    double d = ipd[t]; int id = ipi[t];
    if (d > bd || (d == bd && id < bi)) { bd = d; bi = id; }
  }
  block_argmax(bd, bi, wd, wi);
  const int idx = bi;
  if (tid < Dm) {
    float v = X[(size_t)idx * Dm + tid];
    cent[tid]  = (double)v;
    centf[tid] = v;                      // exact fp32 centroid for the screen
    if (blockIdx.x == 0) {
      Cout[(size_t)ci * Dm + tid] = v;
      Cd[(size_t)ci * Dm + tid]   = (double)v;
    }
  }
  __syncthreads();
  if (tid == 0) {   // serial ascending: bit-identical c2 (do NOT reorder)
    double s = 0.0;
    for (int d = 0; d < Dm; ++d) s += cent[d] * cent[d];
    s_c2 = s;
  }
  __syncthreads();
  const double c2 = s_c2;
  const int g = tid >> 2, Q = tid & 3;
  const double* cq = cent + Q * 32;
  const float2* cf2 = (const float2*)(centf + Q * 32);   // 16 float2
  const int STRIDE = IGB * 64;
  bd = -1.0; bi = 0x7fffffff;

  auto LOADH = [&](int n, uint4* h, double& m, double& xx) {
    const uint4* hr = (const uint4*)(Xh + (size_t)n * Dm + Q * 32);
#pragma unroll
    for (int q = 0; q < 4; ++q) h[q] = hr[q];
    m = mind[n]; xx = x2d[n];            // uniform within 4-lane group
  };
  auto PROCH = [&](int n, const uint4* h, double m, double xx) {
    float a0 = 0.f, a1 = 0.f;
#pragma unroll
    for (int j = 0; j < 4; ++j) {
      union { uint4 u; __half2 p[4]; } U; U.u = h[j];
#pragma unroll
      for (int t = 0; t < 4; ++t) {
        float2 xf = __half22float2(U.p[t]);
        float2 c  = cf2[j * 4 + t];
        a0 = fmaf(xf.x, c.x, a0); a1 = fmaf(xf.y, c.y, a1);
      }
    }
    float dq = a0 + a1;
    dq += dpp_qxor_f(dq, 0xB1); dq += dpp_qxor_f(dq, 0x4E);   // all 4 lanes get sum
    const double ds = c2 + xx - 2.0 * (double)dq;
    double mm = m;
    if (!(ds - m > IMARG)) {             // group-uniform: possible update -> exact
      const float4* xr = (const float4*)(X + (size_t)n * Dm + Q * 32);
      double b0 = 0, b1 = 0, b2 = 0, b3 = 0;
#pragma unroll
      for (int q = 0; q < 8; ++q) {
        float4 v = xr[q];
        b0 += (double)v.x * cq[4*q+0]; b1 += (double)v.y * cq[4*q+1];
        b2 += (double)v.z * cq[4*q+2]; b3 += (double)v.w * cq[4*q+3];
      }
      double dqd = (b0 + b1) + (b2 + b3);
      double d1 = dqd + dpp_qxor_d(dqd, 0xB1);
      double dot = d1 + dpp_qxor_d(d1, 0x4E);
      double d2v = c2 + xx - 2.0 * dot; if (d2v < 0.0) d2v = 0.0;
      if (d2v < mm) mm = d2v;
      if (Q == 0) mind[n] = mm;
    }
    if (Q == 0 && mm > bd) { bd = mm; bi = n; }   // ascending n per lane
  };

  uint4 hA[4], hB[4];
  double mA = 0, xxA = 0, mB = 0, xxB = 0;
  int n = blockIdx.x * 64 + g;           // IGB*64 = 32768 < N: first n valid
  if (n < N) {
    LOADH(n, hA, mA, xxA);
    for (;;) {
      int nn = n + STRIDE;
      if (nn < N) LOADH(nn, hB, mB, xxB);
      PROCH(n, hA, mA, xxA);
      n = nn; if (n >= N) break;
      nn = n + STRIDE;
      if (nn < N) LOADH(nn, hA, mA, xxA);
      PROCH(n, hB, mB, xxB);
      n = nn; if (n >= N) break;
    }
  }
  block_argmax(bd, bi, wd, wi);
  if (tid == 0) { opd[blockIdx.x] = bd; opi[blockIdx.x] = bi; }
}

// fp32 fallback step (3-deep pipeline) — used if ws too small for Xh
__global__ __launch_bounds__(BT, 1) void k_init_step(
    const float* __restrict__ X, float* __restrict__ Cout, double* __restrict__ Cd,
    const double* __restrict__ x2d, double* __restrict__ mind,
    const double* __restrict__ ipd, const int* __restrict__ ipi,
    double* __restrict__ opd, int* __restrict__ opi, int N, int nparts, int ci) {
  __shared__ double cent[Dm];
  __shared__ double wd[4]; __shared__ int wi[4];
  __shared__ double s_c2;
  const int tid = threadIdx.x;
  double bd = -1.0; int bi = 0x7fffffff;
  for (int t = tid; t < nparts; t += BT) {
    double d = ipd[t]; int id = ipi[t];
    if (d > bd || (d == bd && id < bi)) { bd = d; bi = id; }
  }
  block_argmax(bd, bi, wd, wi);
  const int idx = bi;
  if (tid < Dm) {
    float v = X[(size_t)idx * Dm + tid];
    cent[tid] = (double)v;
    if (blockIdx.x == 0) {
      Cout[(size_t)ci * Dm + tid] = v;
      Cd[(size_t)ci * Dm + tid]   = (double)v;
    }
  }
  __syncthreads();
  if (tid == 0) {
    double s = 0.0;
    for (int d = 0; d < Dm; ++d) s += cent[d] * cent[d];
    s_c2 = s;
  }
  __syncthreads();
  const double c2 = s_c2;
  const int g = tid >> 2, Q = tid & 3;
  const double* cq = cent + Q * 32;
  const int STRIDE = IGB * 64;
  bd = -1.0; bi = 0x7fffffff;
  auto LOADB = [&](int n, float4* xv, double& m, double& xx) {
    const float4* xr = (const float4*)(X + (size_t)n * Dm + Q * 32);
#pragma unroll
    for (int q = 0; q < 8; ++q) xv[q] = xr[q];
    if (Q == 0) { m = mind[n]; xx = x2d[n]; }
  };
  auto PROCB = [&](int n, const float4* xv, double m, double xx) {
    double a0 = 0, a1 = 0, a2 = 0, a3 = 0;
#pragma unroll
    for (int q = 0; q < 8; ++q) {
      float4 v = xv[q];
      a0 += (double)v.x * cq[4*q+0]; a1 += (double)v.y * cq[4*q+1];
      a2 += (double)v.z * cq[4*q+2]; a3 += (double)v.w * cq[4*q+3];
    }
    double dq = (a0 + a1) + (a2 + a3);
    double d1 = dq + dpp_qxor_d(dq, 0xB1);
    double dot = d1 + dpp_qxor_d(d1, 0x4E);
    if (Q == 0) {
      double d2 = c2 + xx - 2.0 * dot; if (d2 < 0.0) d2 = 0.0;
      double mm = m; if (d2 < mm) mm = d2;
      mind[n] = mm;
      if (mm > bd) { bd = mm; bi = n; }
    }
  };
  float4 xA[8], xB[8], xC[8];
  double mA = 0, xxA = 0, mB = 0, xxB = 0, mC = 0, xxC = 0;
  int n = blockIdx.x * 64 + g;
  if (n < N) {
    LOADB(n, xA, mA, xxA);
    if (n + STRIDE < N) LOADB(n + STRIDE, xB, mB, xxB);
    if (n + 2 * STRIDE < N) LOADB(n + 2 * STRIDE, xC, mC, xxC);
    for (;;) {
      PROCB(n, xA, mA, xxA);
      if (n + 3 * STRIDE < N) LOADB(n + 3 * STRIDE, xA, mA, xxA);
      n += STRIDE; if (n >= N) break;
      PROCB(n, xB, mB, xxB);
      if (n + 3 * STRIDE < N) LOADB(n + 3 * STRIDE, xB, mB, xxB);
      n += STRIDE; if (n >= N) break;
      PROCB(n, xC, mC, xxC);
      if (n + 3 * STRIDE < N) LOADB(n + 3 * STRIDE, xC, mC, xxC);
      n += STRIDE; if (n >= N) break;
    }
  }
  block_argmax(bd, bi, wd, wi);
  if (tid == 0) { opd[blockIdx.x] = bd; opi[blockIdx.x] = bi; }
}

// final pick (single block): choose C[63], per-row c2 for Lloyd, reset tie_cnt
__global__ __launch_bounds__(256) void k_pick(
    const float* __restrict__ X, float* __restrict__ Cout, double* __restrict__ Cd,
    const double* __restrict__ ipd, const int* __restrict__ ipi, int nparts, int ci,
    double* __restrict__ c2d, float* __restrict__ c2f, int* __restrict__ tie_cnt) {
  __shared__ double cent[Dm];
  __shared__ double wd[4]; __shared__ int wi[4];
  const int tid = threadIdx.x;
  double bd = -1.0; int bi = 0x7fffffff;
  for (int t = tid; t < nparts; t += 256) {
    double d = ipd[t]; int id = ipi[t];
    if (d > bd || (d == bd && id < bi)) { bd = d; bi = id; }
  }
  block_argmax(bd, bi, wd, wi);
  const int idx = bi;
  if (tid < Dm) {
    float v = X[(size_t)idx * Dm + tid];
    cent[tid] = (double)v;
    Cout[(size_t)ci * Dm + tid] = v;
    Cd[(size_t)ci * Dm + tid]   = (double)v;
  }
  __syncthreads();
  if (tid < Kc) {
    double s = 0.0;
    if (tid == ci) { for (int d = 0; d < Dm; ++d) s += cent[d] * cent[d]; }
    else { for (int d = 0; d < Dm; ++d) { double v = Cd[(size_t)tid * Dm + d]; s += v * v; } }
    c2d[tid] = s; c2f[tid] = (float)s;
  }
  if (tid == 0) *tie_cnt = 0;
}

// fp32 screen: 4-lane group (lane = 32 dims) x 4 points per group (empirical wall
// ~100us, R7-R12; residency forcing failed twice). C in padded LDS.
__global__ __launch_bounds__(256, 2) void k_assign(
    const float* __restrict__ X, const float* __restrict__ Cf,
    const float* __restrict__ c2f,
    unsigned char* __restrict__ lbl,
    int* __restrict__ tie_list, int* __restrict__ tie_cnt,
    const int* __restrict__ done_flag, int N) {
  if (*done_flag) return;
  __shared__ float4 cs[Kc * 35];
  __shared__ float c2s[Kc];
  const int tid = threadIdx.x;
  for (int e = tid; e < Kc * D4; e += 256) {
    const int k = e >> 5, j = e & 31;
    cs[k * 35 + (j >> 3) * 9 + (j & 7)] = ((const float4*)Cf)[e];
  }
  if (tid < Kc) c2s[tid] = c2f[tid];
  __syncthreads();
  const int g = tid >> 2, Q = tid & 3;
  const int n0 = blockIdx.x * 256 + g * 4;
  float4 xv[4][8];
#pragma unroll
  for (int j = 0; j < 4; ++j) {
    int p = n0 + j; if (p > N - 1) p = N - 1;
    const float4* xr = (const float4*)(X + (size_t)p * Dm + Q * 32);
#pragma unroll
    for (int q = 0; q < 8; ++q) xv[j][q] = xr[q];
  }
  const float4* myc = cs + Q * 9;
  float best = 3.4028235e38f, second = 3.4028235e38f; int bk = 0;
  for (int k = 0; k < Kc; ++k) {
    const float4* ck = myc + k * 35;
    float a00=0,a01=0,a02=0,a03=0, a10=0,a11=0,a12=0,a13=0;
    float a20=0,a21=0,a22=0,a23=0, a30=0,a31=0,a32=0,a33=0;
#pragma unroll
    for (int q = 0; q < 8; ++q) {
      float4 cv = ck[q];
      a00 += xv[0][q].x*cv.x; a01 += xv[0][q].y*cv.y; a02 += xv[0][q].z*cv.z; a03 += xv[0][q].w*cv.w;
      a10 += xv[1][q].x*cv.x; a11 += xv[1][q].y*cv.y; a12 += xv[1][q].z*cv.z; a13 += xv[1][q].w*cv.w;
      a20 += xv[2][q].x*cv.x; a21 += xv[2][q].y*cv.y; a22 += xv[2][q].z*cv.z; a23 += xv[2][q].w*cv.w;
      a30 += xv[3][q].x*cv.x; a31 += xv[3][q].y*cv.y; a32 += xv[3][q].z*cv.z; a33 += xv[3][q].w*cv.w;
    }
    float d0 = (a00 + a01) + (a02 + a03);
    float d1 = (a10 + a11) + (a12 + a13);
    float d2 = (a20 + a21) + (a22 + a23);
    float d3 = (a30 + a31) + (a32 + a33);
    d0 += dpp_qxor_f(d0, 0xB1); d0 += dpp_qxor_f(d0, 0x4E);
    d1 += dpp_qxor_f(d1, 0xB1); d1 += dpp_qxor_f(d1, 0x4E);
    d2 += dpp_qxor_f(d2, 0xB1); d2 += dpp_qxor_f(d2, 0x4E);
    d3 += dpp_qxor_f(d3, 0xB1); d3 += dpp_qxor_f(d3, 0x4E);
    float mydot = (Q == 0) ? d0 : (Q == 1) ? d1 : (Q == 2) ? d2 : d3;
    float sc = c2s[k] - 2.f * mydot;
    if (sc < best) { second = best; best = sc; bk = k; }
    else if (sc < second) second = sc;
  }
  const int n = n0 + Q;
  if (n < N) {
    lbl[n] = (unsigned char)bk;
    if (second - best < MARGIN) {
      int t = atomicAdd(tie_cnt, 1);
      tie_list[t] = n;
    }
  }
}

// fp64 tie resolution: one WAVE per tie point; lane = cluster.
__global__ __launch_bounds__(256) void k_tie(
    const float* __restrict__ X, const double* __restrict__ Cd,
    const double* __restrict__ c2d,
    const int* __restrict__ tie_list, const int* __restrict__ tie_cnt,
    unsigned char* __restrict__ lbl, const int* __restrict__ done_flag) {
  if (*done_flag) return;
  const int nt = *tie_cnt;
  const int gw = (int)((blockIdx.x * 256 + threadIdx.x) >> 6);
  const int lane = threadIdx.x & 63;
  const int nwaves = gridDim.x * 4;
  const double* cp = Cd + (size_t)lane * Dm;
  const double myc2 = c2d[lane];
  for (int t = gw; t < nt; t += nwaves) {
    const int n = tie_list[t];
    const float4* xr = (const float4*)(X + (size_t)n * Dm);
    double a0 = 0, a1 = 0, a2 = 0, a3 = 0;
#pragma unroll 8
    for (int q = 0; q < D4; ++q) {
      float4 xv = xr[q];
      a0 += (double)xv.x * cp[4*q+0]; a1 += (double)xv.y * cp[4*q+1];
      a2 += (double)xv.z * cp[4*q+2]; a3 += (double)xv.w * cp[4*q+3];
    }
    double sc = myc2 - 2.0 * ((a0 + a1) + (a2 + a3));
    int bk = lane;
#pragma unroll
    for (int off = 32; off; off >>= 1) {
      double osc = __shfl_down(sc, (unsigned)off, 64);
      int    obk = __shfl_down(bk, (unsigned)off, 64);
      if (osc < sc || (osc == sc && obk < bk)) { sc = osc; bk = obk; }
    }
    if (lane == 0) lbl[n] = (unsigned char)bk;
  }
}

// streaming gather-sum with 4-stage software-pipelined prefetch (deterministic).
__global__ __launch_bounds__(256) void k_sum(
    const float* __restrict__ X, const unsigned char* __restrict__ lbl,
    double* __restrict__ spart, int* __restrict__ cpart,
    const int* __restrict__ done_flag, int N, int chunk) {
  if (*done_flag) return;
  __shared__ double acc[2][Kc * Dm];
  __shared__ unsigned int sl[1024];
  __shared__ int cnt[Kc];
  const int tid = threadIdx.x;
  const int s = blockIdx.x;
  const int n0 = s * chunk;
  const int nrows = (N - n0 < chunk) ? (N - n0) : chunk;
  for (int e = tid; e < 2 * Kc * Dm; e += 256) ((double*)acc)[e] = 0.0;
  if (tid < Kc) cnt[tid] = 0;
  const int nw = (nrows > 0) ? ((nrows + 3) >> 2) : 0;
  const unsigned int* lw = (const unsigned int*)(lbl + n0);
  for (int w = tid; w < nw; w += 256) sl[w] = lw[w];
  __syncthreads();
  for (int i = tid; i < nrows; i += 256)
    atomicAdd(&cnt[(sl[i >> 2] >> ((i & 3) * 8)) & 255], 1);
  const int w = tid >> 6, L = tid & 63;
  const int parity = w >> 1, half = w & 1;
  double* ac = acc[parity] + half * 64 + L;
  const float* Xb = X + (size_t)n0 * Dm + half * 64 + L;
  auto LOADC = [&](int base, float* f, int* c) {
#pragma unroll
    for (int u = 0; u < 8; ++u) {
      const int i = base + 2 * u;
      if (i < nrows) {
        c[u] = (int)((sl[i >> 2] >> ((i & 3) * 8)) & 255u);
        f[u] = Xb[(size_t)i * Dm];
      } else c[u] = -1;
    }
  };
  auto PROCC = [&](const float* f, const int* c) {
#pragma unroll
    for (int u = 0; u < 8; ++u)
      if (c[u] >= 0) ac[c[u] * Dm] += (double)f[u];
  };
  float fA[8], fB[8], fC[8], fD[8];
  int   cA[8], cB[8], cC[8], cD[8];
  const int CS = 16;
  LOADC(parity,          fA, cA);
  LOADC(parity + CS,     fB, cB);
  LOADC(parity + 2 * CS, fC, cC);
  for (int cb = parity; cb < nrows; cb += 4 * CS) {
    LOADC(cb + 3 * CS, fD, cD); PROCC(fA, cA);
    LOADC(cb + 4 * CS, fA, cA); PROCC(fB, cB);
    LOADC(cb + 5 * CS, fB, cB); PROCC(fC, cC);
    LOADC(cb + 6 * CS, fC, cC); PROCC(fD, cD);
  }
  __syncthreads();
  for (int e = tid; e < Kc * Dm; e += 256)
    spart[(size_t)s * (Kc * Dm) + e] = acc[0][e] + acc[1][e];
  if (tid < Kc) cpart[s * Kc + tid] = cnt[tid];
}

// per-cluster reduce over slices (fixed ascending order) + mean/shift/c2
__global__ __launch_bounds__(128) void k_update1(
    float* __restrict__ Cout, double* __restrict__ Cd,
    double* __restrict__ c2d, float* __restrict__ c2f,
    const double* __restrict__ spart, const int* __restrict__ cpart,
    double* __restrict__ shiftk, int* __restrict__ empty,
    const int* __restrict__ done_flag, int nslc) {
  if (*done_flag) return;
  __shared__ double red[128];
  __shared__ int ired[128];
  const int k = blockIdx.x, d = threadIdx.x;
  int c = 0;
  for (int s = d; s < nslc; s += 128) c += cpart[s * Kc + k];
  ired[d] = c; __syncthreads();
  for (int t = 64; t; t >>= 1) { if (d < t) ired[d] += ired[d + t]; __syncthreads(); }
  const int cnt = ired[0];
  double sum = 0.0;
#pragma unroll 8
  for (int s = 0; s < nslc; ++s) sum += spart[(size_t)s * (Kc * Dm) + k * Dm + d];
  const double mean = sum / (double)(cnt > 1 ? cnt : 1);
  const double oldv = Cd[k * Dm + d];
  Cd[k * Dm + d] = mean; Cout[k * Dm + d] = (float)mean;
  red[d] = (cnt != 0) ? (mean - oldv) * (mean - oldv) : 0.0;
  __syncthreads();
  for (int t = 64; t; t >>= 1) { if (d < t) red[d] += red[d + t]; __syncthreads(); }
  if (d == 0) shiftk[k] = red[0];
  __syncthreads();
  red[d] = mean * mean; __syncthreads();
  for (int t = 64; t; t >>= 1) { if (d < t) red[d] += red[d + t]; __syncthreads(); }
  if (d == 0) { c2d[k] = red[0]; c2f[k] = (float)red[0]; empty[k] = (cnt == 0); }
}

__global__ void k_update2(const double* __restrict__ shiftk, const int* __restrict__ empty,
                          int* __restrict__ done_flag, int* __restrict__ has_empty,
                          int* __restrict__ tie_cnt) {
  if (*done_flag) return;
  if (threadIdx.x == 0) {
    double sh = 0.0; int any = 0;
    for (int k = 0; k < Kc; ++k) { sh += shiftk[k]; any |= empty[k]; }
    *has_empty = any;
    *tie_cnt = 0;
    if (!any && sh <= TOLd) *done_flag = 1;
  }
}

__global__ __launch_bounds__(BT) void k_far(
    const float* __restrict__ X, const double* __restrict__ Cd,
    const double* __restrict__ c2d, const double* __restrict__ x2d,
    const int* __restrict__ done_flag, const int* __restrict__ has_empty,
    const int* __restrict__ empty,
    double* __restrict__ opd, int* __restrict__ opi, int N) {
  if (*done_flag || !*has_empty) return;
  __shared__ int semp[Kc];
  __shared__ double wd[4]; __shared__ int wi[4];
  if ((int)threadIdx.x < Kc) semp[threadIdx.x] = empty[threadIdx.x];
  __syncthreads();
  const int n = blockIdx.x * BT + threadIdx.x;
  double bd = -1.0; int bi = 0x7fffffff;
  if (n < N) {
    const float4* xr = (const float4*)(X + (size_t)n * Dm);
    float4 xv[D4];
#pragma unroll
    for (int q = 0; q < D4; ++q) xv[q] = xr[q];
    double md = 1e300;
    for (int k = 0; k < Kc; ++k) {
      if (semp[k]) continue;
      double a0 = 0, a1 = 0, a2 = 0, a3 = 0;
      const double* cp = Cd + (size_t)k * Dm;
#pragma unroll
      for (int q = 0; q < D4; ++q) {
        a0 += (double)xv[q].x * cp[4*q+0]; a1 += (double)xv[q].y * cp[4*q+1];
        a2 += (double)xv[q].z * cp[4*q+2]; a3 += (double)xv[q].w * cp[4*q+3];
      }
      double d2v = c2d[k] + x2d[n] - 2.0 * ((a0 + a1) + (a2 + a3));
      if (d2v < 0.0) d2v = 0.0;
      if (d2v < md) md = d2v;
    }
    bd = md; bi = n;
  }
  block_argmax(bd, bi, wd, wi);
  if (threadIdx.x == 0) { opd[blockIdx.x] = bd; opi[blockIdx.x] = bi; }
}

__global__ __launch_bounds__(BT) void k_fix(
    const float* __restrict__ X, float* __restrict__ Cout, double* __restrict__ Cd,
    double* __restrict__ c2d, float* __restrict__ c2f,
    const int* __restrict__ done_flag, const int* __restrict__ has_empty,
    const int* __restrict__ empty,
    const double* __restrict__ ipd, const int* __restrict__ ipi, int nparts) {
  if (*done_flag || !*has_empty) return;
  const int lane = threadIdx.x & 63;
  double bd = -1.0; int bi = 0x7fffffff;
  for (int t = lane; t < nparts; t += 64) {
    double d = ipd[t]; int id = ipi[t];
    if (d > bd || (d == bd && id < bi)) { bd = d; bi = id; }
  }
  wave_argmax(bd, bi);
  const int far = __shfl(bi, 0, 64);
  for (int e = threadIdx.x; e < Kc * Dm; e += BT) {
    if (empty[e >> 7]) {
      float v = X[(size_t)far * Dm + (e & 127)];
      Cout[e] = v; Cd[e] = (double)v;
    }
  }
  __syncthreads();
  if ((int)threadIdx.x < Kc && empty[threadIdx.x]) {
    double s2 = 0.0;
    for (int d = 0; d < Dm; ++d) { double v = Cd[(size_t)threadIdx.x * Dm + d]; s2 += v * v; }
    c2d[threadIdx.x] = s2; c2f[threadIdx.x] = (float)s2;
  }
}

extern "C" void kernel_launch(void* const* d_in, const int* in_sizes, int n_in,
                              void* d_out, int out_size, void* d_ws, size_t ws_size,
                              hipStream_t stream) {
  const float* X = (const float*)d_in[0];
  const int N = in_sizes[0] / Dm;          // 200000
  float* Cout = (float*)d_out;
  (void)n_in; (void)out_size;

  char* w = (char*)d_ws;
  auto alloc = [&](size_t bytes) -> void* {
    void* p = (void*)w; w += (bytes + 255) & ~(size_t)255; return p;
  };
  const size_t NP = ((size_t)N + 255) & ~(size_t)255;
  const int IB  = (N + BT - 1) / BT;       // 782 blocks (1 pt/thread kernels)
  const int ABL = (N + 255) / 256;         // 782 assign blocks
  double* x2d  = (double*)alloc(NP * 8);
  const size_t spart_bytes = (size_t)SLC * Kc * Dm * 8;   // 16.8 MB
  const size_t union_bytes = (spart_bytes > NP * 8) ? spart_bytes : NP * 8;
  double* mind  = (double*)alloc(union_bytes);
  double* spart = mind;
  double* pd0  = (double*)alloc(4096 * 8);
  double* pd1  = (double*)alloc(4096 * 8);
  int*    pi0  = (int*)alloc(4096 * 4);
  int*    pi1  = (int*)alloc(4096 * 4);
  double* Cd   = (double*)alloc((size_t)Kc * Dm * 8);
  double* c2d  = (double*)alloc(Kc * 8);
  float*  c2f  = (float*)alloc(Kc * 4);
  int*    cpart = (int*)alloc(SLC * Kc * 4);
  double* shiftk = (double*)alloc(Kc * 8);
  unsigned char* lbl = (unsigned char*)alloc(NP);
  int*    tie_list = (int*)alloc(NP * 4);
  int*    tie_cnt  = (int*)alloc(4);
  int*    done  = (int*)alloc(4);
  int*    hasem = (int*)alloc(4);
  int*    empty = (int*)alloc(Kc * 4);
  __half* Xh = (__half*)alloc((size_t)N * Dm * 2);        // 51.2 MB fp16 screen copy
  const bool use_h = ((size_t)(w - (char*)d_ws) <= ws_size);

  double* pd[2] = {pd0, pd1};
  int*    pi[2] = {pi0, pi1};

  // ---- farthest-point init: C[0]=X[0], then 63 sequential argmax picks ----
  if (use_h) {
    const int ntot8 = N * Dm / 8;          // 3.2M uint4 groups
    k_prep<<<(ntot8 + 255) / 256, 256, 0, stream>>>((const float4*)X, (uint4*)Xh, ntot8);
  }
  k_init_first<<<IGB, BT, 0, stream>>>(X, Cout, Cd, x2d, mind, pd[0], pi[0], done, N);
  for (int i = 1; i <= 62; ++i) {
    const int rb = (i + 1) & 1, wb = i & 1;
    if (use_h)
      k_init_step_h<<<IGB, BT, 0, stream>>>(X, Xh, Cout, Cd, x2d, mind, pd[rb], pi[rb],
                                            pd[wb], pi[wb], N, IGB, i);
    else
      k_init_step<<<IGB, BT, 0, stream>>>(X, Cout, Cd, x2d, mind, pd[rb], pi[rb],
                                          pd[wb], pi[wb], N, IGB, i);
  }
  k_pick<<<1, 256, 0, stream>>>(X, Cout, Cd, pd[0], pi[0], IGB, 63,
                                c2d, c2f, tie_cnt);   // step 62 wrote buf 0

  // ---- 10 Lloyd iterations ----
  const int chunk = ((N + SLC - 1) / SLC + 3) & ~3;   // 784
  for (int it = 0; it < NITER; ++it) {
    k_assign<<<ABL, 256, 0, stream>>>(X, Cout, c2f, lbl, tie_list, tie_cnt, done, N);
    k_tie<<<128, 256, 0, stream>>>(X, Cd, c2d, tie_list, tie_cnt, lbl, done);
    k_sum<<<SLC, 256, 0, stream>>>(X, lbl, spart, cpart, done, N, chunk);
    k_update1<<<Kc, 128, 0, stream>>>(Cout, Cd, c2d, c2f, spart, cpart,
                                      shiftk, empty, done, SLC);
    k_update2<<<1, 64, 0, stream>>>(shiftk, empty, done, hasem, tie_cnt);
    k_far<<<IB, BT, 0, stream>>>(X, Cd, c2d, x2d, done, hasem, empty, pd0, pi0, N);
    k_fix<<<1, BT, 0, stream>>>(X, Cout, Cd, c2d, c2f, done, hasem, empty, pd0, pi0, IB);
  }
}